// Round 5
// baseline (7325.604 us; speedup 1.0000x reference)
//
#include <hip/hip_runtime.h>
#include <math.h>

#define NN 100000
#define NE 3200000
#define NG 1024
#define FDIM 128
#define NFC1 64
#define NFC2 10

// dst-buckets of 64 rows; edges src-sorted (coarse) within bucket
#define BSH2 6
#define NB2 1563        // ceil(NN/64)
#define CAP2 2560       // mean 2048, sigma 45 -> 11-sigma headroom
#define EPB 16          // edges per thread in bin_kernel
#define KEYSH 9         // src slab = 512 rows = 256KB window granularity
// keys = src>>9 in [0,196)

typedef float fv4 __attribute__((ext_vector_type(4)));

// ---------------- pass 1: bin edges into 1563 dst-buckets of 64 rows -------
// Packed value: (dst & 63) << 17 | src   (src < 2^17)
__global__ __launch_bounds__(256) void bin_kernel(const int* __restrict__ src,
                                                  const int* __restrict__ dst,
                                                  int* __restrict__ gcursor,
                                                  int* __restrict__ staging) {
  __shared__ int hist[NB2];
  __shared__ int base[NB2];
  int t = threadIdx.x;
  for (int i = t; i < NB2; i += 256) hist[i] = 0;
  __syncthreads();
  size_t e0 = (size_t)blockIdx.x * (256 * EPB);
  int bk[EPB], rank[EPB], val[EPB];
#pragma unroll
  for (int j = 0; j < EPB; ++j) {
    size_t e = e0 + (size_t)j * 256 + t;
    if (e < NE) {
      int d = dst[e];
      int s = src[e];
      bk[j] = d >> BSH2;
      val[j] = ((d & 63) << 17) | s;
      rank[j] = atomicAdd(&hist[bk[j]], 1);
    } else {
      bk[j] = -1;
    }
  }
  __syncthreads();
  for (int i = t; i < NB2; i += 256) base[i] = atomicAdd(&gcursor[i], hist[i]);
  __syncthreads();
#pragma unroll
  for (int j = 0; j < EPB; ++j) {
    if (bk[j] >= 0) {
      int pos = base[bk[j]] + rank[j];
      if (pos < CAP2) staging[(size_t)bk[j] * CAP2 + pos] = val[j];
    }
  }
}

// ---------------- pass 2: per-bucket counting sort by coarse src key -------
// Fixed-capacity buckets (no global scan needed): epack[b*CAP2 + i].
__global__ __launch_bounds__(256) void build2_kernel(const int* __restrict__ staging,
                                                     const int* __restrict__ gcursor,
                                                     int* __restrict__ epack) {
  __shared__ int sv[CAP2];
  __shared__ int kcnt[256];
  __shared__ int part[256];
  __shared__ int kcur[256];
  int b = blockIdx.x, t = threadIdx.x;
  int cnt = gcursor[b];
  if (cnt > CAP2) cnt = CAP2;
  kcnt[t] = 0;
  __syncthreads();
  const int* sp = staging + (size_t)b * CAP2;
  for (int i = t; i < cnt; i += 256) {
    int v = sp[i];
    sv[i] = v;
    atomicAdd(&kcnt[(v & 0x1FFFF) >> KEYSH], 1);
  }
  __syncthreads();
  part[t] = kcnt[t];
  __syncthreads();
  for (int st = 1; st < 256; st <<= 1) {
    int u = (t >= st) ? part[t - st] : 0;
    __syncthreads();
    part[t] += u;
    __syncthreads();
  }
  kcur[t] = (t > 0) ? part[t - 1] : 0;
  __syncthreads();
  int* op = epack + (size_t)b * CAP2;
  for (int i = t; i < cnt; i += 256) {
    int v = sv[i];
    int pos = atomicAdd(&kcur[(v & 0x1FFFF) >> KEYSH], 1);
    op[pos] = v;
  }
}

// ---------------- sweep conv: LDS accum gather-aggregate + fused GEMM ------
// Block = 64 dst rows, 512 threads (8 waves), accum[64][128] in LDS (32KB).
// Edges processed in src-ASCENDING order, waves interleaved stride-8, so all
// ~128 concurrent blocks per XCD sweep the same moving src window together
// -> L2 holds only the window, each line fetched ~once per XCD per sweep.
// Blocks >=1024 (generation 2) sweep DESCENDING so their start coincides
// with generation 1's finish region (boustrophedon).
// After barrier: 64x128 GEMM from row-major accum (float4 along k,
// broadcast-read conflict-free), bias+relu, NT store.
// POOL=1 (layer 3): fuse global_sum_pool, no x write.
#define ROWFMA(r, ar)                                              \
  acc[r][0] += ar.x * bv0.x + ar.y * bv1.x + ar.z * bv2.x + ar.w * bv3.x; \
  acc[r][1] += ar.x * bv0.y + ar.y * bv1.y + ar.z * bv2.y + ar.w * bv3.y; \
  acc[r][2] += ar.x * bv0.z + ar.y * bv1.z + ar.z * bv2.z + ar.w * bv3.z; \
  acc[r][3] += ar.x * bv0.w + ar.y * bv1.w + ar.z * bv2.w + ar.w * bv3.w;

template <int POOL>
__global__ __launch_bounds__(512) void sweep_conv(const float2* __restrict__ xin,
                                                  const int* __restrict__ gcursor,
                                                  const int* __restrict__ epack,
                                                  const float* __restrict__ W,
                                                  const float* __restrict__ bias,
                                                  const int* __restrict__ batching,
                                                  float* __restrict__ out,
                                                  float* __restrict__ gout) {
  __shared__ __align__(16) float accum[64 * FDIM];  // 32KB
  __shared__ float gl[8 * FDIM];                    // pool slots (4KB)
  __shared__ int sgv[2];
  int b = blockIdx.x, t = threadIdx.x;
  int w = t >> 6, lane = t & 63;

  fv4* az = (fv4*)accum;
  for (int i = t; i < 64 * FDIM / 4; i += 512) az[i] = (fv4){0.f, 0.f, 0.f, 0.f};
  __syncthreads();

  int cnt = gcursor[b];
  if (cnt > CAP2) cnt = CAP2;
  const int* ep = epack + (size_t)b * CAP2;
  bool rev = (b >= 1024);  // generation-2 blocks sweep descending

  int ii = w;
  for (; ii + 56 < cnt; ii += 64) {
    int v[8];
    float2 xv[8];
#pragma unroll
    for (int j = 0; j < 8; ++j) {
      int idx = ii + 8 * j;
      if (rev) idx = cnt - 1 - idx;
      v[j] = __builtin_amdgcn_readfirstlane(ep[idx]);
    }
#pragma unroll
    for (int j = 0; j < 8; ++j) xv[j] = xin[(size_t)(v[j] & 0x1FFFF) * 64 + lane];
#pragma unroll
    for (int j = 0; j < 8; ++j) {
      int dl = v[j] >> 17;
      atomicAdd(&accum[dl * FDIM + 2 * lane], xv[j].x);
      atomicAdd(&accum[dl * FDIM + 2 * lane + 1], xv[j].y);
    }
  }
  for (; ii < cnt; ii += 8) {
    int idx = rev ? (cnt - 1 - ii) : ii;
    int vv = __builtin_amdgcn_readfirstlane(ep[idx]);
    float2 xv = xin[(size_t)(vv & 0x1FFFF) * 64 + lane];
    int dl = vv >> 17;
    atomicAdd(&accum[dl * FDIM + 2 * lane], xv.x);
    atomicAdd(&accum[dl * FDIM + 2 * lane + 1], xv.y);
  }
  __syncthreads();

  // ---- GEMM 64x128: thread = 4 rows x 4 cols ----
  int rg = lane >> 5, c = lane & 31;
  int rbase = w * 8 + rg * 4;
  float acc[4][4];
#pragma unroll
  for (int r = 0; r < 4; ++r)
#pragma unroll
    for (int j = 0; j < 4; ++j) acc[r][j] = 0.f;

  const fv4* A = (const fv4*)accum;  // [64][32] float4 view
#pragma unroll 4
  for (int k4 = 0; k4 < 32; ++k4) {
    fv4 a0 = A[(rbase + 0) * 32 + k4];
    fv4 a1 = A[(rbase + 1) * 32 + k4];
    fv4 a2 = A[(rbase + 2) * 32 + k4];
    fv4 a3 = A[(rbase + 3) * 32 + k4];
    float4 bv0 = *(const float4*)(W + (4 * k4 + 0) * FDIM + c * 4);
    float4 bv1 = *(const float4*)(W + (4 * k4 + 1) * FDIM + c * 4);
    float4 bv2 = *(const float4*)(W + (4 * k4 + 2) * FDIM + c * 4);
    float4 bv3 = *(const float4*)(W + (4 * k4 + 3) * FDIM + c * 4);
    ROWFMA(0, a0)
    ROWFMA(1, a1)
    ROWFMA(2, a2)
    ROWFMA(3, a3)
  }

  int rowbase = b << BSH2;
  float4 b4 = *(const float4*)(bias + c * 4);

  if (POOL == 0) {
#pragma unroll
    for (int r = 0; r < 4; ++r) {
      int row = rowbase + rbase + r;
      if (row < NN) {
        fv4 o;
        o.x = fmaxf(acc[r][0] + b4.x, 0.f);
        o.y = fmaxf(acc[r][1] + b4.y, 0.f);
        o.z = fmaxf(acc[r][2] + b4.z, 0.f);
        o.w = fmaxf(acc[r][3] + b4.w, 0.f);
        __builtin_nontemporal_store(o, (fv4*)(out + (size_t)row * FDIM + c * 4));
      }
    }
  } else {
    if (t == 0) {
      sgv[0] = batching[rowbase];
      int last = rowbase + 63;
      if (last >= NN) last = NN - 1;
      sgv[1] = batching[last] - sgv[0] + 1;
    }
    for (int i = t; i < 8 * FDIM; i += 512) gl[i] = 0.f;
    __syncthreads();
    int g0 = sgv[0], nG = sgv[1];
    if (nG <= 8) {
#pragma unroll
      for (int r = 0; r < 4; ++r) {
        int row = rowbase + rbase + r;
        if (row < NN) {
          int slot = batching[row] - g0;
          atomicAdd(&gl[slot * FDIM + c * 4 + 0], fmaxf(acc[r][0] + b4.x, 0.f));
          atomicAdd(&gl[slot * FDIM + c * 4 + 1], fmaxf(acc[r][1] + b4.y, 0.f));
          atomicAdd(&gl[slot * FDIM + c * 4 + 2], fmaxf(acc[r][2] + b4.z, 0.f));
          atomicAdd(&gl[slot * FDIM + c * 4 + 3], fmaxf(acc[r][3] + b4.w, 0.f));
        }
      }
      __syncthreads();
      for (int i = t; i < nG * FDIM; i += 512) {
        float v = gl[i];
        if (v != 0.f)
          atomicAdd(&gout[(size_t)(g0 + (i >> 7)) * FDIM + (i & 127)], v);
      }
    } else {
#pragma unroll
      for (int r = 0; r < 4; ++r) {
        int row = rowbase + rbase + r;
        if (row < NN) {
          int gid = batching[row];
          atomicAdd(&gout[(size_t)gid * FDIM + c * 4 + 0], fmaxf(acc[r][0] + b4.x, 0.f));
          atomicAdd(&gout[(size_t)gid * FDIM + c * 4 + 1], fmaxf(acc[r][1] + b4.y, 0.f));
          atomicAdd(&gout[(size_t)gid * FDIM + c * 4 + 2], fmaxf(acc[r][2] + b4.z, 0.f));
          atomicAdd(&gout[(size_t)gid * FDIM + c * 4 + 3], fmaxf(acc[r][3] + b4.w, 0.f));
        }
      }
    }
  }
}

// ---------------- head: FC1 + FC2 + softmax over pooled g ----------------
__global__ __launch_bounds__(128) void head(const float* __restrict__ g,
                                            const float* __restrict__ Wf1,
                                            const float* __restrict__ bf1,
                                            const float* __restrict__ Wf2,
                                            const float* __restrict__ bf2,
                                            float* __restrict__ out) {
  __shared__ float gl[128];
  __shared__ float hl[64];
  __shared__ float ol[10];
  __shared__ float red[2];
  int gid = blockIdx.x, t = threadIdx.x;
  gl[t] = g[(size_t)gid * FDIM + t];
  __syncthreads();
  if (t < NFC1) {
    float h = bf1[t];
    for (int f = 0; f < 128; ++f) h += gl[f] * Wf1[f * NFC1 + t];
    hl[t] = h;
  }
  __syncthreads();
  if (t < NFC2) {
    float o = bf2[t];
    for (int i = 0; i < NFC1; ++i) o += hl[i] * Wf2[i * NFC2 + t];
    ol[t] = o;
  }
  __syncthreads();
  if (t == 0) {
    float m = ol[0];
    for (int i = 1; i < NFC2; ++i) m = fmaxf(m, ol[i]);
    float s = 0.f;
    for (int i = 0; i < NFC2; ++i) s += expf(ol[i] - m);
    red[0] = m;
    red[1] = s;
  }
  __syncthreads();
  if (t < NFC2) out[(size_t)gid * NFC2 + t] = expf(ol[t] - red[0]) / red[1];
}

extern "C" void kernel_launch(void* const* d_in, const int* in_sizes, int n_in,
                              void* d_out, int out_size, void* d_ws, size_t ws_size,
                              hipStream_t stream) {
  const float* node_attr = (const float*)d_in[0];
  const float* Wc = (const float*)d_in[1];   // [3][128][128]
  const float* bc = (const float*)d_in[2];   // [3][128]
  const float* Wf1 = (const float*)d_in[3];  // [128][64]
  const float* bf1 = (const float*)d_in[4];
  const float* Wf2 = (const float*)d_in[5];  // [64][10]
  const float* bf2 = (const float*)d_in[6];
  const int* src = (const int*)d_in[7];
  const int* dst = (const int*)d_in[8];
  const int* batching = (const int*)d_in[9];
  float* out = (float*)d_out;

  char* wsp = (char*)d_ws;
  size_t off = 0;
  auto alloc = [&](size_t bytes) -> void* {
    void* p = wsp + off;
    off += (bytes + 255) & ~(size_t)255;
    return p;
  };
  int* gcursor = (int*)alloc((size_t)NB2 * sizeof(int));
  int* epack = (int*)alloc((size_t)NB2 * CAP2 * sizeof(int));   // 16.0 MB
  float* bufA = (float*)alloc((size_t)NN * FDIM * sizeof(float));  // 51.2 MB
  float* bufB = (float*)alloc((size_t)NN * FDIM * sizeof(float));  // 51.2 MB
  // staging (16 MB) aliases bufB: dead before conv2 writes bufB
  int* staging = (int*)bufB;
  // pooled g (512 KB) aliases bufA: bufA dead after conv2 reads it
  float* gbuf = (float*)bufA;

  // edge binning + per-bucket coarse src sort
  hipMemsetAsync(gcursor, 0, (size_t)NB2 * sizeof(int), stream);
  bin_kernel<<<(NE + 256 * EPB - 1) / (256 * EPB), 256, 0, stream>>>(src, dst, gcursor, staging);
  build2_kernel<<<NB2, 256, 0, stream>>>(staging, gcursor, epack);

  // layer 1: bufA = relu(agg(node_attr) @ W0 + b0)
  sweep_conv<0><<<NB2, 512, 0, stream>>>((const float2*)node_attr, gcursor, epack,
                                         Wc, bc, nullptr, bufA, nullptr);
  // layer 2: bufB = relu(agg(bufA) @ W1 + b1)
  sweep_conv<0><<<NB2, 512, 0, stream>>>((const float2*)bufA, gcursor, epack,
                                         Wc + 16384, bc + 128, nullptr, bufB, nullptr);
  // layer 3 fused with global_sum_pool
  hipMemsetAsync(gbuf, 0, (size_t)NG * FDIM * sizeof(float), stream);
  sweep_conv<1><<<NB2, 512, 0, stream>>>((const float2*)bufB, gcursor, epack,
                                         Wc + 32768, bc + 256, batching, nullptr, gbuf);

  // head
  head<<<NG, 128, 0, stream>>>(gbuf, Wf1, bf1, Wf2, bf2, out);
}

// Round 6
// 1028.121 us; speedup vs baseline: 7.1252x; 7.1252x over previous
//
#include <hip/hip_runtime.h>
#include <math.h>

#define NN 100000
#define NE 3200000
#define NG 1024
#define FDIM 128
#define NFC1 64
#define NFC2 10

#define BSHIFT 9
#define NBUCK 196   // ceil(NN/512)
#define CAP 20480   // mean 16384, sigma ~127 -> 32-sigma headroom
#define EPB 16      // edges per thread in bin_kernel

typedef float fv4 __attribute__((ext_vector_type(4)));

// ---------------- pass 1: bin edges into 196 coarse buckets ----------------
// Packed value: (dst & 511) << 17 | src   (src < 2^17, dst_local < 2^9)
__global__ __launch_bounds__(256) void bin_kernel(const int* __restrict__ src,
                                                  const int* __restrict__ dst,
                                                  int* __restrict__ gcursor,
                                                  int* __restrict__ staging) {
  __shared__ int hist[NBUCK];
  __shared__ int base[NBUCK];
  int t = threadIdx.x;
  for (int i = t; i < NBUCK; i += 256) hist[i] = 0;
  __syncthreads();
  size_t e0 = (size_t)blockIdx.x * (256 * EPB);
  int bk[EPB], rank[EPB], val[EPB];
#pragma unroll
  for (int j = 0; j < EPB; ++j) {
    size_t e = e0 + (size_t)j * 256 + t;
    if (e < NE) {
      int d = dst[e];
      int s = src[e];
      bk[j] = d >> BSHIFT;
      val[j] = ((d & 511) << 17) | s;
      rank[j] = atomicAdd(&hist[bk[j]], 1);
    } else {
      bk[j] = -1;
    }
  }
  __syncthreads();
  for (int i = t; i < NBUCK; i += 256) base[i] = atomicAdd(&gcursor[i], hist[i]);
  __syncthreads();
#pragma unroll
  for (int j = 0; j < EPB; ++j) {
    if (bk[j] >= 0) {
      int pos = base[bk[j]] + rank[j];
      if (pos < CAP) staging[(size_t)bk[j] * CAP + pos] = val[j];
    }
  }
}

// ---------------- pass 2: per-bucket CSR finalize (scan fused in) ----------------
__global__ __launch_bounds__(256) void build_kernel(const int* __restrict__ staging,
                                                    const int* __restrict__ gcursor,
                                                    int* __restrict__ row_off,
                                                    int* __restrict__ esrc) {
  __shared__ int ncnt[512];
  __shared__ int noff[513];
  __shared__ int part[256];
  __shared__ int sscan[256];
  int b = blockIdx.x, t = threadIdx.x;
  int gv = (t < NBUCK) ? gcursor[t] : 0;
  sscan[t] = gv;
  __syncthreads();
  for (int st = 1; st < 256; st <<= 1) {
    int u = (t >= st) ? sscan[t - st] : 0;
    __syncthreads();
    sscan[t] += u;
    __syncthreads();
  }
  int cnt = gcursor[b];
  int ebase = sscan[b] - cnt;  // exclusive prefix
  int nbase = b << BSHIFT;
  ncnt[t] = 0;
  ncnt[t + 256] = 0;
  __syncthreads();
  const int* sp = staging + (size_t)b * CAP;
  for (int i = t; i < cnt; i += 256) {
    int dl = sp[i] >> 17;
    atomicAdd(&ncnt[dl], 1);
  }
  __syncthreads();
  int a0 = ncnt[2 * t], a1 = ncnt[2 * t + 1];
  part[t] = a0 + a1;
  __syncthreads();
  for (int st = 1; st < 256; st <<= 1) {
    int u = (t >= st) ? part[t - st] : 0;
    __syncthreads();
    part[t] += u;
    __syncthreads();
  }
  int excl = (t > 0) ? part[t - 1] : 0;
  noff[2 * t] = excl;
  noff[2 * t + 1] = excl + a0;
  if (t == 255) noff[512] = part[255];
  __syncthreads();
  for (int i = t; i <= 512; i += 256) {
    int n = nbase + i;
    if (n <= NN) row_off[n] = ebase + noff[i];
  }
  // reuse ncnt as write cursors
  ncnt[2 * t] = noff[2 * t];
  ncnt[2 * t + 1] = noff[2 * t + 1];
  __syncthreads();
  for (int i = t; i < cnt; i += 256) {
    int v = sp[i];
    int dl = v >> 17;
    int pos = atomicAdd(&ncnt[dl], 1);
    esrc[ebase + pos] = v & 0x1FFFF;
  }
}

// ---------------- fused conv layer: out = relu(gather(xin)@W + bias) ----------------
// R1-measured-best structure (271.7 us/layer): 512 threads = 8 waves; 64 dst
// nodes per block. Phase 1: paired-edge dwordx4 gather (lanes 0-31 read edge
// e's 512B row, lanes 32-63 edge e+1; 8 dwordx4 in flight), __shfl_xor(32)
// combine, transposed LDS store. Phase 2: 64x128 GEMM, 4x4 acc/thread, W
// streamed from L1. POOL=1 (layer 3): fuse global_sum_pool into the epilogue
// (proven R4/R5): LDS per-graph slots + one global atomic per (graph,feat);
// no x write.
template <int POOL>
__global__ __launch_bounds__(512) void conv_fused(const float4* __restrict__ xin,
                                                  const int* __restrict__ row_off,
                                                  const int* __restrict__ esrc,
                                                  const float* __restrict__ W,
                                                  const float* __restrict__ bias,
                                                  const int* __restrict__ batching,
                                                  float* __restrict__ out,
                                                  float* __restrict__ gout) {
  __shared__ __align__(16) float aT[128 * 68];
  __shared__ float gl[8 * FDIM];
  __shared__ int sgv[2];
  int t = threadIdx.x;
  int w = t >> 6;
  int lane = t & 63;
  int half = lane >> 5;   // which edge of the pair this lane reads
  int c4 = lane & 31;     // which float4 of the 512B row
  int nodebase = blockIdx.x * 64;

  // ---- phase 1: gather-aggregate 8 nodes for this wave ----
  for (int i = 0; i < 8; ++i) {
    int r = w * 8 + i;
    int node = nodebase + r;
    int beg = 0, end = 0;
    if (node < NN) {
      beg = __builtin_amdgcn_readfirstlane(row_off[node]);
      end = __builtin_amdgcn_readfirstlane(row_off[node + 1]);
    }
    float4 acc = make_float4(0.f, 0.f, 0.f, 0.f);
    int e = beg;
    for (; e + 16 <= end; e += 16) {
      int i0 = __builtin_amdgcn_readfirstlane(esrc[e + 0]);
      int i1 = __builtin_amdgcn_readfirstlane(esrc[e + 1]);
      int i2 = __builtin_amdgcn_readfirstlane(esrc[e + 2]);
      int i3 = __builtin_amdgcn_readfirstlane(esrc[e + 3]);
      int i4 = __builtin_amdgcn_readfirstlane(esrc[e + 4]);
      int i5 = __builtin_amdgcn_readfirstlane(esrc[e + 5]);
      int i6 = __builtin_amdgcn_readfirstlane(esrc[e + 6]);
      int i7 = __builtin_amdgcn_readfirstlane(esrc[e + 7]);
      int i8 = __builtin_amdgcn_readfirstlane(esrc[e + 8]);
      int i9 = __builtin_amdgcn_readfirstlane(esrc[e + 9]);
      int i10 = __builtin_amdgcn_readfirstlane(esrc[e + 10]);
      int i11 = __builtin_amdgcn_readfirstlane(esrc[e + 11]);
      int i12 = __builtin_amdgcn_readfirstlane(esrc[e + 12]);
      int i13 = __builtin_amdgcn_readfirstlane(esrc[e + 13]);
      int i14 = __builtin_amdgcn_readfirstlane(esrc[e + 14]);
      int i15 = __builtin_amdgcn_readfirstlane(esrc[e + 15]);
      float4 v0 = xin[(size_t)(half ? i1 : i0) * 32 + c4];
      float4 v1 = xin[(size_t)(half ? i3 : i2) * 32 + c4];
      float4 v2 = xin[(size_t)(half ? i5 : i4) * 32 + c4];
      float4 v3 = xin[(size_t)(half ? i7 : i6) * 32 + c4];
      float4 v4 = xin[(size_t)(half ? i9 : i8) * 32 + c4];
      float4 v5 = xin[(size_t)(half ? i11 : i10) * 32 + c4];
      float4 v6 = xin[(size_t)(half ? i13 : i12) * 32 + c4];
      float4 v7 = xin[(size_t)(half ? i15 : i14) * 32 + c4];
      acc.x += ((v0.x + v1.x) + (v2.x + v3.x)) + ((v4.x + v5.x) + (v6.x + v7.x));
      acc.y += ((v0.y + v1.y) + (v2.y + v3.y)) + ((v4.y + v5.y) + (v6.y + v7.y));
      acc.z += ((v0.z + v1.z) + (v2.z + v3.z)) + ((v4.z + v5.z) + (v6.z + v7.z));
      acc.w += ((v0.w + v1.w) + (v2.w + v3.w)) + ((v4.w + v5.w) + (v6.w + v7.w));
    }
    for (; e + 8 <= end; e += 8) {
      int i0 = __builtin_amdgcn_readfirstlane(esrc[e + 0]);
      int i1 = __builtin_amdgcn_readfirstlane(esrc[e + 1]);
      int i2 = __builtin_amdgcn_readfirstlane(esrc[e + 2]);
      int i3 = __builtin_amdgcn_readfirstlane(esrc[e + 3]);
      int i4 = __builtin_amdgcn_readfirstlane(esrc[e + 4]);
      int i5 = __builtin_amdgcn_readfirstlane(esrc[e + 5]);
      int i6 = __builtin_amdgcn_readfirstlane(esrc[e + 6]);
      int i7 = __builtin_amdgcn_readfirstlane(esrc[e + 7]);
      float4 v0 = xin[(size_t)(half ? i1 : i0) * 32 + c4];
      float4 v1 = xin[(size_t)(half ? i3 : i2) * 32 + c4];
      float4 v2 = xin[(size_t)(half ? i5 : i4) * 32 + c4];
      float4 v3 = xin[(size_t)(half ? i7 : i6) * 32 + c4];
      acc.x += (v0.x + v1.x) + (v2.x + v3.x);
      acc.y += (v0.y + v1.y) + (v2.y + v3.y);
      acc.z += (v0.z + v1.z) + (v2.z + v3.z);
      acc.w += (v0.w + v1.w) + (v2.w + v3.w);
    }
    for (; e + 2 <= end; e += 2) {
      int i0 = __builtin_amdgcn_readfirstlane(esrc[e + 0]);
      int i1 = __builtin_amdgcn_readfirstlane(esrc[e + 1]);
      float4 v = xin[(size_t)(half ? i1 : i0) * 32 + c4];
      acc.x += v.x;
      acc.y += v.y;
      acc.z += v.z;
      acc.w += v.w;
    }
    if (e < end) {
      int i0 = __builtin_amdgcn_readfirstlane(esrc[e]);
      if (half == 0) {
        float4 v = xin[(size_t)i0 * 32 + c4];
        acc.x += v.x;
        acc.y += v.y;
        acc.z += v.z;
        acc.w += v.w;
      }
    }
    acc.x += __shfl_xor(acc.x, 32);
    acc.y += __shfl_xor(acc.y, 32);
    acc.z += __shfl_xor(acc.z, 32);
    acc.w += __shfl_xor(acc.w, 32);
    if (half == 0) {
      aT[(4 * c4 + 0) * 68 + r] = acc.x;
      aT[(4 * c4 + 1) * 68 + r] = acc.y;
    } else {
      aT[(4 * c4 + 2) * 68 + r] = acc.z;
      aT[(4 * c4 + 3) * 68 + r] = acc.w;
    }
  }
  __syncthreads();

  // ---- phase 2: GEMM 64x128 tile ----
  int rg = lane >> 5;       // 0..1
  int c = lane & 31;        // cols 4c..4c+3
  int rbase = w * 8 + rg * 4;

  float acc[4][4];
#pragma unroll
  for (int r = 0; r < 4; ++r)
#pragma unroll
    for (int j = 0; j < 4; ++j) acc[r][j] = 0.f;

#pragma unroll 4
  for (int k = 0; k < 128; ++k) {
    float4 bv = *(const float4*)(W + k * FDIM + c * 4);
    float4 a0 = *(const float4*)(&aT[k * 68 + rbase]);
    float ar[4] = {a0.x, a0.y, a0.z, a0.w};
#pragma unroll
    for (int r = 0; r < 4; ++r) {
      acc[r][0] += ar[r] * bv.x;
      acc[r][1] += ar[r] * bv.y;
      acc[r][2] += ar[r] * bv.z;
      acc[r][3] += ar[r] * bv.w;
    }
  }

  float4 b4 = *(const float4*)(bias + c * 4);

  if (POOL == 0) {
#pragma unroll
    for (int r = 0; r < 4; ++r) {
      int row = nodebase + rbase + r;
      if (row < NN) {
        float4 o;
        o.x = fmaxf(acc[r][0] + b4.x, 0.f);
        o.y = fmaxf(acc[r][1] + b4.y, 0.f);
        o.z = fmaxf(acc[r][2] + b4.z, 0.f);
        o.w = fmaxf(acc[r][3] + b4.w, 0.f);
        *(float4*)(out + (size_t)row * FDIM + c * 4) = o;
      }
    }
  } else {
    // fused global_sum_pool: batching is sorted, so a 64-row tile spans ~2-3
    // graphs. LDS-reduce per graph slot, then one global atomic per
    // (graph, feature). Fallback to direct atomics if >8 graphs.
    if (t == 0) {
      sgv[0] = batching[nodebase];
      int last = nodebase + 63;
      if (last >= NN) last = NN - 1;
      sgv[1] = batching[last] - sgv[0] + 1;
    }
    for (int i = t; i < 8 * FDIM; i += 512) gl[i] = 0.f;
    __syncthreads();
    int g0 = sgv[0], nG = sgv[1];
    if (nG <= 8) {
#pragma unroll
      for (int r = 0; r < 4; ++r) {
        int row = nodebase + rbase + r;
        if (row < NN) {
          int slot = batching[row] - g0;
          atomicAdd(&gl[slot * FDIM + c * 4 + 0], fmaxf(acc[r][0] + b4.x, 0.f));
          atomicAdd(&gl[slot * FDIM + c * 4 + 1], fmaxf(acc[r][1] + b4.y, 0.f));
          atomicAdd(&gl[slot * FDIM + c * 4 + 2], fmaxf(acc[r][2] + b4.z, 0.f));
          atomicAdd(&gl[slot * FDIM + c * 4 + 3], fmaxf(acc[r][3] + b4.w, 0.f));
        }
      }
      __syncthreads();
      for (int i = t; i < nG * FDIM; i += 512) {
        float v = gl[i];
        if (v != 0.f)
          atomicAdd(&gout[(size_t)(g0 + (i >> 7)) * FDIM + (i & 127)], v);
      }
    } else {
#pragma unroll
      for (int r = 0; r < 4; ++r) {
        int row = nodebase + rbase + r;
        if (row < NN) {
          int gid = batching[row];
          atomicAdd(&gout[(size_t)gid * FDIM + c * 4 + 0], fmaxf(acc[r][0] + b4.x, 0.f));
          atomicAdd(&gout[(size_t)gid * FDIM + c * 4 + 1], fmaxf(acc[r][1] + b4.y, 0.f));
          atomicAdd(&gout[(size_t)gid * FDIM + c * 4 + 2], fmaxf(acc[r][2] + b4.z, 0.f));
          atomicAdd(&gout[(size_t)gid * FDIM + c * 4 + 3], fmaxf(acc[r][3] + b4.w, 0.f));
        }
      }
    }
  }
}

// ---------------- head: FC1 + FC2 + softmax over pooled g ----------------
__global__ __launch_bounds__(128) void head(const float* __restrict__ g,
                                            const float* __restrict__ Wf1,
                                            const float* __restrict__ bf1,
                                            const float* __restrict__ Wf2,
                                            const float* __restrict__ bf2,
                                            float* __restrict__ out) {
  __shared__ float gl[128];
  __shared__ float hl[64];
  __shared__ float ol[10];
  __shared__ float red[2];
  int gid = blockIdx.x, t = threadIdx.x;
  gl[t] = g[(size_t)gid * FDIM + t];
  __syncthreads();
  if (t < NFC1) {
    float h = bf1[t];
    for (int f = 0; f < 128; ++f) h += gl[f] * Wf1[f * NFC1 + t];
    hl[t] = h;
  }
  __syncthreads();
  if (t < NFC2) {
    float o = bf2[t];
    for (int i = 0; i < NFC1; ++i) o += hl[i] * Wf2[i * NFC2 + t];
    ol[t] = o;
  }
  __syncthreads();
  if (t == 0) {
    float m = ol[0];
    for (int i = 1; i < NFC2; ++i) m = fmaxf(m, ol[i]);
    float s = 0.f;
    for (int i = 0; i < NFC2; ++i) s += expf(ol[i] - m);
    red[0] = m;
    red[1] = s;
  }
  __syncthreads();
  if (t < NFC2) out[(size_t)gid * NFC2 + t] = expf(ol[t] - red[0]) / red[1];
}

extern "C" void kernel_launch(void* const* d_in, const int* in_sizes, int n_in,
                              void* d_out, int out_size, void* d_ws, size_t ws_size,
                              hipStream_t stream) {
  const float* node_attr = (const float*)d_in[0];
  const float* Wc = (const float*)d_in[1];   // [3][128][128]
  const float* bc = (const float*)d_in[2];   // [3][128]
  const float* Wf1 = (const float*)d_in[3];  // [128][64]
  const float* bf1 = (const float*)d_in[4];
  const float* Wf2 = (const float*)d_in[5];  // [64][10]
  const float* bf2 = (const float*)d_in[6];
  const int* src = (const int*)d_in[7];
  const int* dst = (const int*)d_in[8];
  const int* batching = (const int*)d_in[9];
  float* out = (float*)d_out;

  char* wsp = (char*)d_ws;
  size_t off = 0;
  auto alloc = [&](size_t bytes) -> void* {
    void* p = wsp + off;
    off += (bytes + 255) & ~(size_t)255;
    return p;
  };
  int* row_off = (int*)alloc((size_t)(NN + 1) * sizeof(int));
  int* gcursor = (int*)alloc(NBUCK * sizeof(int));
  int* esrc = (int*)alloc((size_t)NE * sizeof(int));
  float* bufA = (float*)alloc((size_t)NN * FDIM * sizeof(float));
  float* bufB = (float*)alloc((size_t)NN * FDIM * sizeof(float));
  // staging (16.1 MB) aliases bufB: staging is dead before layer-2 writes bufB
  int* staging = (int*)bufB;
  // pooled g (512 KB) aliases bufA: bufA is dead after layer-2's gather reads it
  float* gbuf = (float*)bufA;

  // CSR build via 2-level counting sort
  hipMemsetAsync(gcursor, 0, NBUCK * sizeof(int), stream);
  bin_kernel<<<(NE + 256 * EPB - 1) / (256 * EPB), 256, 0, stream>>>(src, dst, gcursor, staging);
  build_kernel<<<NBUCK, 256, 0, stream>>>(staging, gcursor, row_off, esrc);

  const int GRID = (NN + 63) / 64;  // 1563

  // layer 1: bufA = relu(agg(node_attr) @ W0 + b0)
  conv_fused<0><<<GRID, 512, 0, stream>>>((const float4*)node_attr, row_off, esrc,
                                          Wc, bc, nullptr, bufA, nullptr);
  // layer 2: bufB = relu(agg(bufA) @ W1 + b1)
  conv_fused<0><<<GRID, 512, 0, stream>>>((const float4*)bufA, row_off, esrc,
                                          Wc + 16384, bc + 128, nullptr, bufB, nullptr);
  // layer 3 fused with global_sum_pool (no x3 write); gbuf aliases bufA,
  // memset is stream-ordered after layer-2 finished reading bufA
  hipMemsetAsync(gbuf, 0, (size_t)NG * FDIM * sizeof(float), stream);
  conv_fused<1><<<GRID, 512, 0, stream>>>((const float4*)bufB, row_off, esrc,
                                          Wc + 32768, bc + 256, batching, nullptr, gbuf);

  // head
  head<<<NG, 128, 0, stream>>>(gbuf, Wf1, bf1, Wf2, bf2, out);
}

// Round 7
// 721.352 us; speedup vs baseline: 10.1554x; 1.4253x over previous
//
#include <hip/hip_runtime.h>
#include <hip/hip_fp16.h>
#include <math.h>

#define NN 100000
#define NE 3200000
#define NG 1024
#define FDIM 128
#define NFC1 64
#define NFC2 10

#define BSHIFT 9
#define NBUCK 196   // ceil(NN/512)
#define CAP 20480   // mean 16384, sigma ~127 -> 32-sigma headroom
#define EPB 16      // edges per thread in bin_kernel

#define RF __builtin_amdgcn_readfirstlane
// quarter-select: quarter q of the wave takes value k_q (static indices only)
#define QSEL(q, v0, v1, v2, v3) ((q) == 0 ? (v0) : (q) == 1 ? (v1) : (q) == 2 ? (v2) : (v3))

// ---------------- pass 1: bin edges into 196 coarse buckets ----------------
// Packed value: (dst & 511) << 17 | src   (src < 2^17, dst_local < 2^9)
__global__ __launch_bounds__(256) void bin_kernel(const int* __restrict__ src,
                                                  const int* __restrict__ dst,
                                                  int* __restrict__ gcursor,
                                                  int* __restrict__ staging) {
  __shared__ int hist[NBUCK];
  __shared__ int base[NBUCK];
  int t = threadIdx.x;
  for (int i = t; i < NBUCK; i += 256) hist[i] = 0;
  __syncthreads();
  size_t e0 = (size_t)blockIdx.x * (256 * EPB);
  int bk[EPB], rank[EPB], val[EPB];
#pragma unroll
  for (int j = 0; j < EPB; ++j) {
    size_t e = e0 + (size_t)j * 256 + t;
    if (e < NE) {
      int d = dst[e];
      int s = src[e];
      bk[j] = d >> BSHIFT;
      val[j] = ((d & 511) << 17) | s;
      rank[j] = atomicAdd(&hist[bk[j]], 1);
    } else {
      bk[j] = -1;
    }
  }
  __syncthreads();
  for (int i = t; i < NBUCK; i += 256) base[i] = atomicAdd(&gcursor[i], hist[i]);
  __syncthreads();
#pragma unroll
  for (int j = 0; j < EPB; ++j) {
    if (bk[j] >= 0) {
      int pos = base[bk[j]] + rank[j];
      if (pos < CAP) staging[(size_t)bk[j] * CAP + pos] = val[j];
    }
  }
}

// ---------------- pass 2: per-bucket CSR finalize (scan fused in) ----------------
__global__ __launch_bounds__(256) void build_kernel(const int* __restrict__ staging,
                                                    const int* __restrict__ gcursor,
                                                    int* __restrict__ row_off,
                                                    int* __restrict__ esrc) {
  __shared__ int ncnt[512];
  __shared__ int noff[513];
  __shared__ int part[256];
  __shared__ int sscan[256];
  int b = blockIdx.x, t = threadIdx.x;
  int gv = (t < NBUCK) ? gcursor[t] : 0;
  sscan[t] = gv;
  __syncthreads();
  for (int st = 1; st < 256; st <<= 1) {
    int u = (t >= st) ? sscan[t - st] : 0;
    __syncthreads();
    sscan[t] += u;
    __syncthreads();
  }
  int cnt = gcursor[b];
  int ebase = sscan[b] - cnt;  // exclusive prefix
  int nbase = b << BSHIFT;
  ncnt[t] = 0;
  ncnt[t + 256] = 0;
  __syncthreads();
  const int* sp = staging + (size_t)b * CAP;
  for (int i = t; i < cnt; i += 256) {
    int dl = sp[i] >> 17;
    atomicAdd(&ncnt[dl], 1);
  }
  __syncthreads();
  int a0 = ncnt[2 * t], a1 = ncnt[2 * t + 1];
  part[t] = a0 + a1;
  __syncthreads();
  for (int st = 1; st < 256; st <<= 1) {
    int u = (t >= st) ? part[t - st] : 0;
    __syncthreads();
    part[t] += u;
    __syncthreads();
  }
  int excl = (t > 0) ? part[t - 1] : 0;
  noff[2 * t] = excl;
  noff[2 * t + 1] = excl + a0;
  if (t == 255) noff[512] = part[255];
  __syncthreads();
  for (int i = t; i <= 512; i += 256) {
    int n = nbase + i;
    if (n <= NN) row_off[n] = ebase + noff[i];
  }
  // reuse ncnt as write cursors
  ncnt[2 * t] = noff[2 * t];
  ncnt[2 * t + 1] = noff[2 * t + 1];
  __syncthreads();
  for (int i = t; i < cnt; i += 256) {
    int v = sp[i];
    int dl = v >> 17;
    int pos = atomicAdd(&ncnt[dl], 1);
    esrc[ebase + pos] = v & 0x1FFFF;
  }
}

// ---------------- fp32 -> fp16 convert (node_attr -> xh0) ----------------
__global__ __launch_bounds__(256) void cvt_kernel(const float4* __restrict__ in,
                                                  uint2* __restrict__ outp, int n) {
  int i = blockIdx.x * 256 + threadIdx.x;
  int stride = gridDim.x * 256;
  for (; i < n; i += stride) {
    float4 v = in[i];
    union { __half2 h; unsigned u; } u0, u1;
    u0.h = __float22half2_rn(make_float2(v.x, v.y));
    u1.h = __float22half2_rn(make_float2(v.z, v.w));
    outp[i] = make_uint2(u0.u, u1.u);
  }
}

// ---------------- fused conv layer: out = relu(gather(xh)@W + bias) -------
// Gather path is fp16 (row = 128 half = 256B); ALL arithmetic fp32.
// 512 threads = 8 waves; 64 dst nodes/block. Quad-edge gather: wave quarter
// q (16 lanes) reads edge e+q; lane chunk c (lane&15) reads 16B = 8 halfs.
// 4 quads in flight (16 edges, 64B/lane). Cross-quarter combine via
// shfl_xor(16)+shfl_xor(32); transposed LDS store; fp32 64x128 GEMM
// (4x4 acc/thread, W from L1). POOL=0: fp16 output store (half4 = 8B).
// POOL=1 (layer 3): fp32 global_sum_pool epilogue, no x write.
template <int POOL>
__global__ __launch_bounds__(512) void conv_fused(const float4* __restrict__ xh4,
                                                  const int* __restrict__ row_off,
                                                  const int* __restrict__ esrc,
                                                  const float* __restrict__ W,
                                                  const float* __restrict__ bias,
                                                  const int* __restrict__ batching,
                                                  __half* __restrict__ out,
                                                  float* __restrict__ gout) {
  __shared__ __align__(16) float aT[128 * 68];
  __shared__ float gl[8 * FDIM];
  __shared__ int sgv[2];
  int t = threadIdx.x;
  int w = t >> 6;
  int lane = t & 63;
  int q = lane >> 4;   // edge within quad
  int c = lane & 15;   // 16B chunk within the 256B fp16 row
  int nodebase = blockIdx.x * 64;

#define CVTACC(fv)                                         \
  {                                                        \
    union { float4 f; __half2 h[4]; } u_;                  \
    u_.f = (fv);                                           \
    float2 p_;                                             \
    p_ = __half22float2(u_.h[0]); a[0] += p_.x; a[1] += p_.y; \
    p_ = __half22float2(u_.h[1]); a[2] += p_.x; a[3] += p_.y; \
    p_ = __half22float2(u_.h[2]); a[4] += p_.x; a[5] += p_.y; \
    p_ = __half22float2(u_.h[3]); a[6] += p_.x; a[7] += p_.y; \
  }

  // ---- phase 1: gather-aggregate 8 nodes for this wave ----
  for (int i = 0; i < 8; ++i) {
    int r = w * 8 + i;
    int node = nodebase + r;
    int beg = 0, end = 0;
    if (node < NN) {
      beg = RF(row_off[node]);
      end = RF(row_off[node + 1]);
    }
    float a[8] = {0.f, 0.f, 0.f, 0.f, 0.f, 0.f, 0.f, 0.f};
    int e = beg;
    // main: 16 edges / iter (4 quads, 4 x dwordx4 in flight per lane)
    for (; e + 16 <= end; e += 16) {
      int a0 = RF(esrc[e + 0]), a1 = RF(esrc[e + 1]), a2 = RF(esrc[e + 2]), a3 = RF(esrc[e + 3]);
      int b0 = RF(esrc[e + 4]), b1 = RF(esrc[e + 5]), b2 = RF(esrc[e + 6]), b3 = RF(esrc[e + 7]);
      int c0 = RF(esrc[e + 8]), c1 = RF(esrc[e + 9]), c2 = RF(esrc[e + 10]), c3 = RF(esrc[e + 11]);
      int d0 = RF(esrc[e + 12]), d1 = RF(esrc[e + 13]), d2 = RF(esrc[e + 14]), d3 = RF(esrc[e + 15]);
      int iA = QSEL(q, a0, a1, a2, a3);
      int iB = QSEL(q, b0, b1, b2, b3);
      int iC = QSEL(q, c0, c1, c2, c3);
      int iD = QSEL(q, d0, d1, d2, d3);
      float4 fA = xh4[(size_t)iA * 16 + c];
      float4 fB = xh4[(size_t)iB * 16 + c];
      float4 fC = xh4[(size_t)iC * 16 + c];
      float4 fD = xh4[(size_t)iD * 16 + c];
      CVTACC(fA)
      CVTACC(fB)
      CVTACC(fC)
      CVTACC(fD)
    }
    // mid tail: 8 edges / iter (2 quads)
    for (; e + 8 <= end; e += 8) {
      int a0 = RF(esrc[e + 0]), a1 = RF(esrc[e + 1]), a2 = RF(esrc[e + 2]), a3 = RF(esrc[e + 3]);
      int b0 = RF(esrc[e + 4]), b1 = RF(esrc[e + 5]), b2 = RF(esrc[e + 6]), b3 = RF(esrc[e + 7]);
      int iA = QSEL(q, a0, a1, a2, a3);
      int iB = QSEL(q, b0, b1, b2, b3);
      float4 fA = xh4[(size_t)iA * 16 + c];
      float4 fB = xh4[(size_t)iB * 16 + c];
      CVTACC(fA)
      CVTACC(fB)
    }
    // final: predicated quad (esrc padded +8 ints, so scalar reads stay in-bounds;
    // lanes with e+q >= end skip the vector load, so garbage indices are never used)
    for (; e < end; e += 4) {
      int a0 = RF(esrc[e + 0]), a1 = RF(esrc[e + 1]), a2 = RF(esrc[e + 2]), a3 = RF(esrc[e + 3]);
      int iA = QSEL(q, a0, a1, a2, a3);
      float4 fA = make_float4(0.f, 0.f, 0.f, 0.f);
      if (e + q < end) fA = xh4[(size_t)iA * 16 + c];
      CVTACC(fA)
    }
    // combine quarters: lanes {c, c+16, c+32, c+48} hold partials of chunk c
#pragma unroll
    for (int j = 0; j < 8; ++j) {
      a[j] += __shfl_xor(a[j], 16);
      a[j] += __shfl_xor(a[j], 32);
    }
    // transposed store: feature f = c*8 + j; this lane writes j = 2q, 2q+1
    float w0 = QSEL(q, a[0], a[2], a[4], a[6]);
    float w1 = QSEL(q, a[1], a[3], a[5], a[7]);
    aT[(c * 8 + 2 * q + 0) * 68 + r] = w0;
    aT[(c * 8 + 2 * q + 1) * 68 + r] = w1;
  }
  __syncthreads();

  // ---- phase 2: GEMM 64x128 tile (fp32) ----
  int rg = lane >> 5;       // 0..1
  int cc = lane & 31;       // cols 4cc..4cc+3
  int rbase = w * 8 + rg * 4;

  float acc[4][4];
#pragma unroll
  for (int r = 0; r < 4; ++r)
#pragma unroll
    for (int j = 0; j < 4; ++j) acc[r][j] = 0.f;

#pragma unroll 4
  for (int k = 0; k < 128; ++k) {
    float4 bv = *(const float4*)(W + k * FDIM + cc * 4);
    float4 a0 = *(const float4*)(&aT[k * 68 + rbase]);
    float ar[4] = {a0.x, a0.y, a0.z, a0.w};
#pragma unroll
    for (int r = 0; r < 4; ++r) {
      acc[r][0] += ar[r] * bv.x;
      acc[r][1] += ar[r] * bv.y;
      acc[r][2] += ar[r] * bv.z;
      acc[r][3] += ar[r] * bv.w;
    }
  }

  float4 b4 = *(const float4*)(bias + cc * 4);

  if (POOL == 0) {
#pragma unroll
    for (int r = 0; r < 4; ++r) {
      int row = nodebase + rbase + r;
      if (row < NN) {
        float ox = fmaxf(acc[r][0] + b4.x, 0.f);
        float oy = fmaxf(acc[r][1] + b4.y, 0.f);
        float oz = fmaxf(acc[r][2] + b4.z, 0.f);
        float ow = fmaxf(acc[r][3] + b4.w, 0.f);
        union { uint2 u2; __half2 h[2]; } pk;
        pk.h[0] = __float22half2_rn(make_float2(ox, oy));
        pk.h[1] = __float22half2_rn(make_float2(oz, ow));
        *(uint2*)(out + (size_t)row * FDIM + cc * 4) = pk.u2;
      }
    }
  } else {
    // fused global_sum_pool (fp32): batching sorted, 64-row tile spans ~2-3
    // graphs; LDS slots + one global atomic per (graph, feature).
    if (t == 0) {
      sgv[0] = batching[nodebase];
      int last = nodebase + 63;
      if (last >= NN) last = NN - 1;
      sgv[1] = batching[last] - sgv[0] + 1;
    }
    for (int i = t; i < 8 * FDIM; i += 512) gl[i] = 0.f;
    __syncthreads();
    int g0 = sgv[0], nG = sgv[1];
    if (nG <= 8) {
#pragma unroll
      for (int r = 0; r < 4; ++r) {
        int row = nodebase + rbase + r;
        if (row < NN) {
          int slot = batching[row] - g0;
          atomicAdd(&gl[slot * FDIM + cc * 4 + 0], fmaxf(acc[r][0] + b4.x, 0.f));
          atomicAdd(&gl[slot * FDIM + cc * 4 + 1], fmaxf(acc[r][1] + b4.y, 0.f));
          atomicAdd(&gl[slot * FDIM + cc * 4 + 2], fmaxf(acc[r][2] + b4.z, 0.f));
          atomicAdd(&gl[slot * FDIM + cc * 4 + 3], fmaxf(acc[r][3] + b4.w, 0.f));
        }
      }
      __syncthreads();
      for (int i = t; i < nG * FDIM; i += 512) {
        float v = gl[i];
        if (v != 0.f)
          atomicAdd(&gout[(size_t)(g0 + (i >> 7)) * FDIM + (i & 127)], v);
      }
    } else {
#pragma unroll
      for (int r = 0; r < 4; ++r) {
        int row = nodebase + rbase + r;
        if (row < NN) {
          int gid = batching[row];
          atomicAdd(&gout[(size_t)gid * FDIM + cc * 4 + 0], fmaxf(acc[r][0] + b4.x, 0.f));
          atomicAdd(&gout[(size_t)gid * FDIM + cc * 4 + 1], fmaxf(acc[r][1] + b4.y, 0.f));
          atomicAdd(&gout[(size_t)gid * FDIM + cc * 4 + 2], fmaxf(acc[r][2] + b4.z, 0.f));
          atomicAdd(&gout[(size_t)gid * FDIM + cc * 4 + 3], fmaxf(acc[r][3] + b4.w, 0.f));
        }
      }
    }
  }
#undef CVTACC
}

// ---------------- head: FC1 + FC2 + softmax over pooled g ----------------
__global__ __launch_bounds__(128) void head(const float* __restrict__ g,
                                            const float* __restrict__ Wf1,
                                            const float* __restrict__ bf1,
                                            const float* __restrict__ Wf2,
                                            const float* __restrict__ bf2,
                                            float* __restrict__ out) {
  __shared__ float gl[128];
  __shared__ float hl[64];
  __shared__ float ol[10];
  __shared__ float red[2];
  int gid = blockIdx.x, t = threadIdx.x;
  gl[t] = g[(size_t)gid * FDIM + t];
  __syncthreads();
  if (t < NFC1) {
    float h = bf1[t];
    for (int f = 0; f < 128; ++f) h += gl[f] * Wf1[f * NFC1 + t];
    hl[t] = h;
  }
  __syncthreads();
  if (t < NFC2) {
    float o = bf2[t];
    for (int i = 0; i < NFC1; ++i) o += hl[i] * Wf2[i * NFC2 + t];
    ol[t] = o;
  }
  __syncthreads();
  if (t == 0) {
    float m = ol[0];
    for (int i = 1; i < NFC2; ++i) m = fmaxf(m, ol[i]);
    float s = 0.f;
    for (int i = 0; i < NFC2; ++i) s += expf(ol[i] - m);
    red[0] = m;
    red[1] = s;
  }
  __syncthreads();
  if (t < NFC2) out[(size_t)gid * NFC2 + t] = expf(ol[t] - red[0]) / red[1];
}

extern "C" void kernel_launch(void* const* d_in, const int* in_sizes, int n_in,
                              void* d_out, int out_size, void* d_ws, size_t ws_size,
                              hipStream_t stream) {
  const float* node_attr = (const float*)d_in[0];
  const float* Wc = (const float*)d_in[1];   // [3][128][128]
  const float* bc = (const float*)d_in[2];   // [3][128]
  const float* Wf1 = (const float*)d_in[3];  // [128][64]
  const float* bf1 = (const float*)d_in[4];
  const float* Wf2 = (const float*)d_in[5];  // [64][10]
  const float* bf2 = (const float*)d_in[6];
  const int* src = (const int*)d_in[7];
  const int* dst = (const int*)d_in[8];
  const int* batching = (const int*)d_in[9];
  float* out = (float*)d_out;

  char* wsp = (char*)d_ws;
  size_t off = 0;
  auto alloc = [&](size_t bytes) -> void* {
    void* p = wsp + off;
    off += (bytes + 255) & ~(size_t)255;
    return p;
  };
  int* row_off = (int*)alloc((size_t)(NN + 1) * sizeof(int));
  int* gcursor = (int*)alloc(NBUCK * sizeof(int));
  int* esrc = (int*)alloc((size_t)(NE + 8) * sizeof(int));  // +8 pad for quad over-read
  __half* xh0 = (__half*)alloc((size_t)NN * FDIM * sizeof(__half));   // 25.6 MB
  __half* bufA = (__half*)alloc((size_t)NN * FDIM * sizeof(__half));  // 25.6 MB
  __half* bufB = (__half*)alloc((size_t)NN * FDIM * sizeof(__half));  // 25.6 MB
  // staging (16.1 MB) aliases bufB: staging is dead (consumed by build_kernel)
  // before layer-2 writes bufB
  int* staging = (int*)bufB;
  // pooled g (512 KB fp32) aliases bufA: bufA dead after layer-2's gather;
  // memset enqueued after layer-2 launch (stream-ordered)
  float* gbuf = (float*)bufA;

  // CSR build via 2-level counting sort
  hipMemsetAsync(gcursor, 0, NBUCK * sizeof(int), stream);
  bin_kernel<<<(NE + 256 * EPB - 1) / (256 * EPB), 256, 0, stream>>>(src, dst, gcursor, staging);
  build_kernel<<<NBUCK, 256, 0, stream>>>(staging, gcursor, row_off, esrc);

  // node_attr fp32 -> fp16
  cvt_kernel<<<2048, 256, 0, stream>>>((const float4*)node_attr, (uint2*)xh0,
                                       NN * FDIM / 4);

  const int GRID = (NN + 63) / 64;  // 1563

  // layer 1: bufA = fp16(relu(agg(xh0) @ W0 + b0))
  conv_fused<0><<<GRID, 512, 0, stream>>>((const float4*)xh0, row_off, esrc,
                                          Wc, bc, nullptr, bufA, nullptr);
  // layer 2: bufB = fp16(relu(agg(bufA) @ W1 + b1))
  conv_fused<0><<<GRID, 512, 0, stream>>>((const float4*)bufA, row_off, esrc,
                                          Wc + 16384, bc + 128, nullptr, bufB, nullptr);
  // layer 3 fused with global_sum_pool (fp32 epilogue, no x3 write)
  hipMemsetAsync(gbuf, 0, (size_t)NG * FDIM * sizeof(float), stream);
  conv_fused<1><<<GRID, 512, 0, stream>>>((const float4*)bufB, row_off, esrc,
                                          Wc + 32768, bc + 256, batching, nullptr, gbuf);

  // head
  head<<<NG, 128, 0, stream>>>(gbuf, Wf1, bf1, Wf2, bf2, out);
}